// Round 11
// baseline (324.162 us; speedup 1.0000x reference)
//
#include <hip/hip_runtime.h>
#include <hip/hip_fp16.h>
#include <math.h>

// DiagonalLSTM: B=8, Cin=HID=128, H=64, W=64, K=2, T = 2W-1 = 127 steps.
//
// Round 25 design (single launch; contention-free overlap):
//   - R24 post-mortem: overlap cost (+67us) persisted with 1 block/CU ->
//     interference is the MEMORY system, not CU sharing. zpre's 8B-at-1KB-
//     stride zph stores (33.5M scattered transactions, WRITE_SIZE 72MB w/
//     partial-line writebacks) inflate lstm's serial-chain load latencies.
//   - Fix 1: zpre stages each 32-pos half-tile in padded LDS (ztile[32][520])
//     then copies out as lane-consecutive uint4 -> fully coalesced stores.
//   - Fix 2: 128 zpre blocks x 4 tiles (tt = j + 128*i: rows 0..15 done in
//     round 1, matching lstm consumption), w_is frags converted once/block.
//     Grid 32+128=160 <= 256 CUs -> no co-residency; lstm at setprio(1).
//   - Fix 3: ONE kernel launch. hx sentinel via hipMemsetAsync(0xFF) (the
//     sentinel IS 0xFF fill; memset proven graph-safe in fallback), zflag
//     via memset(0); lstm blocks self-convert wfrag from w_ss (mapping
//     verified vs prep_k) and write a private bias slot (vmcnt-drained).
//   - lstm loop byte-identical to proven R19/R24; flag/fence protocol
//     byte-identical to R23/R24 (3x proven).

#define HID 128
#define BB 8
#define HH 64
#define WW 64
#define TT 127

#define NZB 128   // zpre blocks (4 tiles each)
#define HROW 136  // padded LDS row stride in halfs

// LDS union: lstm h_lds = 2*9*2*136*2 = 9792 B
//            zpre xt 64*136*2 = 17408 B + ztile 32*520*2 = 33280 B = 50688 B
#define SMEM_BYTES 50688
#define XT_BYTES 17408

typedef _Float16 v8h __attribute__((ext_vector_type(8)));
typedef float v4f __attribute__((ext_vector_type(4)));

#define SENT64 0xFFFFFFFFFFFFFFFFULL  // 4x f16 -NaN (0xFF fill pattern)

__device__ __forceinline__ float fsig(float x) {
  float e = __builtin_amdgcn_exp2f(x * -1.44269504f);
  return __builtin_amdgcn_rcpf(1.f + e);
}
__device__ __forceinline__ float ftanh_(float x) {
  float e = __builtin_amdgcn_exp2f(x * 2.88539009f);
  return __builtin_fmaf(-2.f, __builtin_amdgcn_rcpf(1.f + e), 1.f);
}

// Step barrier: LDS-visibility only (no vmcnt drain; see R15 notes).
#define STEP_BARRIER()                                   \
  do {                                                   \
    asm volatile("s_waitcnt lgkmcnt(0)" ::: "memory");   \
    __builtin_amdgcn_s_barrier();                        \
    asm volatile("" ::: "memory");                       \
  } while (0)

#define HPLD(p) __hip_atomic_load((p), __ATOMIC_RELAXED, __HIP_MEMORY_SCOPE_AGENT)

// ---------------- R19 step body + one-time lazy zflag wait ----------------
#define STEP_BODY(T, RB)                                                       \
  do {                                                                         \
    /* phase 0: chain-0 LDS reads (slot rl) issued ASAP after barrier */       \
    v8h bfr[4];                                                                \
    _Pragma("unroll") for (int kt = 0; kt < 4; kt++)                           \
        bfr[kt] = *(const v8h*)&h_lds[RB][(rl * 2 + bl) * HROW + kt * 32 +     \
                                          quad * 8];                           \
    /* convert zu -> v4f (chain-1 C-operand init) */                           \
    v4f zi[4];                                                                 \
    _Pragma("unroll") for (int g = 0; g < 4; g++)                              \
        _Pragma("unroll") for (int i = 0; i < 4; i++)                          \
        zi[g][i] = __half2float(zu.h[g * 4 + i]);                              \
    /* zp prefetch for T+1; one-time flag wait at first in-band prefetch */    \
    {                                                                          \
      if (!zdone && (unsigned)wn < WW) {                                       \
        while (__hip_atomic_load(zf, __ATOMIC_RELAXED,                         \
                                 __HIP_MEMORY_SCOPE_AGENT) == 0u)              \
          __builtin_amdgcn_s_sleep(2);                                         \
        __builtin_amdgcn_fence(__ATOMIC_ACQUIRE, "agent");                     \
        zdone = true;                                                          \
      }                                                                        \
      const uint4* p = (const uint4*)(((unsigned)wn < WW) ? zcur : zbias);     \
      zu.q[0] = p[0];                                                          \
      zu.q[1] = p[1];                                                          \
      wn++;                                                                    \
      zcur += 512;                                                             \
    }                                                                          \
    /* MFMA: two independent 4-link chains; chain-1 accumulates onto z */      \
    v4f acc0[4], acc1[4];                                                      \
    _Pragma("unroll") for (int g = 0; g < 4; g++) {                            \
      acc0[g] = (v4f){0.f, 0.f, 0.f, 0.f};                                     \
      acc1[g] = zi[g];                                                         \
    }                                                                          \
    _Pragma("unroll") for (int kt = 0; kt < 4; kt++) {                         \
      _Pragma("unroll") for (int g = 0; g < 4; g++)                            \
          acc0[g] = __builtin_amdgcn_mfma_f32_16x16x32_f16(                    \
              wfrag[g][kt], bfr[kt], acc0[g], 0, 0, 0);                        \
    }                                                                          \
    _Pragma("unroll") for (int kt = 0; kt < 4; kt++) {                         \
      v8h bf1 = *(const v8h*)&h_lds[RB][((rl + 1) * 2 + bl) * HROW + kt * 32 + \
                                        quad * 8];                             \
      _Pragma("unroll") for (int g = 0; g < 4; g++)                            \
          acc1[g] = __builtin_amdgcn_mfma_f32_16x16x32_f16(                    \
              wfrag[g][4 + kt], bf1, acc1[g], 0, 0, 0);                        \
    }                                                                          \
    /* mid-step hx boundary load (R19 lazy): gates/pack/stores cover it */     \
    unsigned long long pend = 0ull;                                            \
    if (is_cons) pend = HPLD(ca);                                              \
    /* gates (bias pre-folded into zph -> rides in acc1) */                    \
    const int w = (T)-r;                                                       \
    const bool inband = ((unsigned)w < WW);                                    \
    float hv[4];                                                               \
    _Pragma("unroll") for (int rg2 = 0; rg2 < 4; rg2++) {                      \
      float z0 = acc0[0][rg2] + acc1[0][rg2];                                  \
      float z1 = acc0[1][rg2] + acc1[1][rg2];                                  \
      float z2 = acc0[2][rg2] + acc1[2][rg2];                                  \
      float z3 = acc0[3][rg2] + acc1[3][rg2];                                  \
      float iv = fsig(z0);                                                     \
      float fv = fsig(z1);                                                     \
      float ov = fsig(z2);                                                     \
      float gv = ftanh_(z3);                                                   \
      c[rg2] = fv * c[rg2] + iv * gv;                                          \
      hv[rg2] = ov * ftanh_(c[rg2]);                                           \
    }                                                                          \
    /* h(T) -> write-buffer slots 1..8 (LDS, 8B per lane) */                   \
    __half2 plo = __floats2half2_rn(hv[0], hv[1]);                             \
    __half2 phi = __floats2half2_rn(hv[2], hv[3]);                             \
    {                                                                          \
      uint2 pk;                                                                \
      pk.x = *(unsigned*)&plo;                                                 \
      pk.y = *(unsigned*)&phi;                                                 \
      *(uint2*)&h_lds[(RB) ^ 1][((rl + 1) * 2 + bl) * HROW + uq0] = pk;        \
    }                                                                          \
    /* export h(T)[R0+7]: fire-and-forget (data == flag, no drain) */          \
    if (rgr < 7 && l15 >= 14) {                                                \
      unsigned long long pk =                                                  \
          ((unsigned long long)*(unsigned*)&phi << 32) | *(unsigned*)&plo;     \
      __hip_atomic_store(pa_hx, pk, __ATOMIC_RELAXED,                          \
                         __HIP_MEMORY_SCOPE_AGENT);                            \
    }                                                                          \
    pa_hx += 2048;                                                             \
    /* out shift-window; coalesced 16B flush every 4 steps per cell */         \
    _Pragma("unroll") for (int rg2 = 0; rg2 < 4; rg2++) {                      \
      outb[rg2].x = outb[rg2].y;                                               \
      outb[rg2].y = outb[rg2].z;                                               \
      outb[rg2].z = outb[rg2].w;                                               \
      outb[rg2].w = hv[rg2];                                                   \
    }                                                                          \
    if (inband && (w & 3) == 3) {                                              \
      *(float4*)op0 = outb[0];                                                 \
      *(float4*)op1 = outb[1];                                                 \
      *(float4*)op2 = outb[2];                                                 \
      *(float4*)op3 = outb[3];                                                 \
      op0 += 4; op1 += 4; op2 += 4; op3 += 4;                                  \
    }                                                                          \
    /* validate pend (hx[T] = h(T)[R0-1]) -> wb slot 0 */                      \
    if (is_cons) {                                                             \
      while (__ballot(pend == SENT64) != 0ull) {                               \
        __builtin_amdgcn_s_sleep(1);                                           \
        pend = HPLD(ca);                                                       \
      }                                                                        \
      *(unsigned long long*)&h_lds[(RB) ^ 1][(0 * 2 + ebl) * HROW + eu] =      \
          pend;                                                                \
    }                                                                          \
    ca += 2048;                                                                \
    STEP_BARRIER();                                                            \
  } while (0)

// ---- fused kernel: blocks 0..31 lstm, blocks 32..159 zpre (4 tiles) ----
__global__ __launch_bounds__(512, 1) void fused(
    const __half* __restrict__ zph, unsigned long long* __restrict__ hx,
    float* __restrict__ out, const float* __restrict__ x,
    const float* __restrict__ w_is, const float* __restrict__ w_ss,
    const float* __restrict__ b_is, const float* __restrict__ b_ss,
    unsigned* __restrict__ zflag, __half* __restrict__ zphw) {
  __shared__ __align__(16) char smem[SMEM_BYTES];

  const int blk = blockIdx.x;
  const int tid = threadIdx.x;
  const int L = tid & 63;
  const int quad = L >> 4;
  const int l15 = L & 15;

  if (blk >= 32) {
    // ================= zpre block: tiles tt = j + 128*i =================
    _Float16(*xt)[136] = (_Float16(*)[136])smem;
    _Float16(*zt)[520] = (_Float16(*)[520])(smem + XT_BYTES);
    const int j = blk - 32;    // 0..127
    const int wv8 = tid >> 6;  // 0..7; wave owns mt = 4*wv8 + m

    // w_is A-frags + bias, loaded ONCE (tile-independent):
    v8h wfr[4][4];
    float4 bvv[4];
#pragma unroll
    for (int m = 0; m < 4; m++) {
      const int mt = 4 * wv8 + m;
      const int O = mt * 16 + l15;
#pragma unroll
      for (int kt = 0; kt < 4; kt++) {
        const float* p = w_is + (size_t)O * 128 + kt * 32 + quad * 8;
        float4 a = *(const float4*)p;
        float4 b2 = *(const float4*)(p + 4);
        v8h f;
        f[0] = (_Float16)a.x;  f[1] = (_Float16)a.y;
        f[2] = (_Float16)a.z;  f[3] = (_Float16)a.w;
        f[4] = (_Float16)b2.x; f[5] = (_Float16)b2.y;
        f[6] = (_Float16)b2.z; f[7] = (_Float16)b2.w;
        wfr[m][kt] = f;
      }
      const int O4 = mt * 16 + quad * 4;
      float4 bi = *(const float4*)&b_is[O4];
      float4 bs4 = *(const float4*)&b_ss[O4];
      bvv[m] = make_float4(bi.x + bs4.x, bi.y + bs4.y, bi.z + bs4.z,
                           bi.w + bs4.w);
    }

    for (int it = 0; it < 4; it++) {
      const int tt = j + NZB * it;  // round 1 = rows 0..15 (consumer order)
      const int r = tt >> 3;
      const int b = tt & 7;

      __syncthreads();  // xt/zt free
      // stage x(b,:,r,:) -> xt transposed [w][c], 512-thread coalesced
      {
        const int cw = tid >> 4;        // 0..31
        const int w4 = (tid & 15) * 4;  // w base
#pragma unroll
        for (int p = 0; p < 4; p++) {
          int cc = p * 32 + cw;
          float4 v =
              *(const float4*)&x[(((size_t)b * 128 + cc) * HH + r) * WW + w4];
          xt[w4 + 0][cc] = (_Float16)v.x;
          xt[w4 + 1][cc] = (_Float16)v.y;
          xt[w4 + 2][cc] = (_Float16)v.z;
          xt[w4 + 3][cc] = (_Float16)v.w;
        }
      }
      __syncthreads();

      // two half-tiles of 32 pos: compute -> ztile (LDS) -> coalesced copy
#pragma unroll
      for (int p = 0; p < 2; p++) {
#pragma unroll
        for (int ntl = 0; ntl < 2; ntl++) {
          const int nt = 2 * p + ntl;
          v8h bf[4];
#pragma unroll
          for (int kt = 0; kt < 4; kt++)
            bf[kt] = *(const v8h*)&xt[nt * 16 + l15][kt * 32 + quad * 8];
#pragma unroll
          for (int m = 0; m < 4; m++) {
            v4f acc = (v4f){0.f, 0.f, 0.f, 0.f};
#pragma unroll
            for (int kt = 0; kt < 4; kt++)
              acc = __builtin_amdgcn_mfma_f32_16x16x32_f16(wfr[m][kt], bf[kt],
                                                           acc, 0, 0, 0);
            const int mt = 4 * wv8 + m;
            __half2 lo =
                __floats2half2_rn(acc[0] + bvv[m].x, acc[1] + bvv[m].y);
            __half2 hi =
                __floats2half2_rn(acc[2] + bvv[m].z, acc[3] + bvv[m].w);
            uint2 pk;
            pk.x = *(unsigned*)&lo;
            pk.y = *(unsigned*)&hi;
            *(uint2*)&zt[ntl * 16 + l15][((mt & 7) * 4 + quad) * 16 +
                                         (mt >> 3) * 4] = pk;
          }
        }
        __syncthreads();  // ztile complete
        // copy out 32 pos x 512 halfs, lane-consecutive uint4 (coalesced)
        const size_t gbase = ((((size_t)b * HH + r) * WW) + p * 32) * 512;
#pragma unroll
        for (int k2 = 0; k2 < 4; k2++) {
          int u = tid + k2 * 512;  // uint4 index 0..2047
          int oh = u * 8;          // half index
          uint4 v = *(const uint4*)&zt[oh >> 9][oh & 511];
          *(uint4*)&zphw[gbase + oh] = v;
        }
        __syncthreads();  // drain before ztile reuse / flag
      }

      if (tid == 0) {
        __builtin_amdgcn_fence(__ATOMIC_RELEASE, "agent");
        __hip_atomic_store(&zflag[tt], 1u, __ATOMIC_RELAXED,
                           __HIP_MEMORY_SCOPE_AGENT);
      }
    }
    return;
  }

  // ================= lstm block (R19 loop; self-contained prologue) =======
  __builtin_amdgcn_s_setprio(1);  // win CU arbitration vs any co-resident work
  _Float16(*h_lds)[9 * 2 * HROW] = (_Float16(*)[9 * 2 * HROW])smem;

  const int rgr = blk >> 2;
  const int bg = blk & 3;
  const int R0 = rgr * 8;
  const int wv = tid >> 6;
  const int rl = l15 >> 1;
  const int bl = l15 & 1;
  const int b = bg * 2 + bl;
  const int r = R0 + rl;
  const int uq0 = 16 * wv + quad * 4;
  const int zoff = (4 * wv + quad) * 16;

  for (int i = tid; i < (2 * 9 * 2 * HROW) / 2; i += 512)
    ((unsigned*)smem)[i] = 0u;

  // ---- private bias slot (1 half per thread; drained before t=0 use) ----
  {
    int g = (tid >> 2) & 3;
    int u2 = (tid >> 4) * 4 + (tid & 3);
    int O = g * 128 + u2;
    zphw[(size_t)BB * HH * WW * 512 + blk * 512 + tid] =
        __float2half(b_is[O] + b_ss[O]);
  }

  // ---- wfrag self-converted from w_ss (verified vs prep_k mapping):
  // wfrag[g][kt] lane L elem j = k<128 ? w_ss[O*256+2k] : w_ss[O*256+2(k-128)+1]
  // with O=(8g+wv)*16+l15, k=kt*32+quad*8+j. Even/odd pairs share cachelines:
  // one 16-float run per (g,kt2) yields kt2 (evens) and kt2+4 (odds).
  v8h wfrag[4][8];
#pragma unroll
  for (int g = 0; g < 4; g++) {
    const float* wb = w_ss + (size_t)((8 * g + wv) * 16 + l15) * 256;
#pragma unroll
    for (int kt2 = 0; kt2 < 4; kt2++) {
      const float4* p4 = (const float4*)(wb + kt2 * 64 + quad * 16);
      float4 f0 = p4[0], f1 = p4[1], f2 = p4[2], f3 = p4[3];
      v8h e, o;
      e[0] = (_Float16)f0.x; e[1] = (_Float16)f0.z;
      e[2] = (_Float16)f1.x; e[3] = (_Float16)f1.z;
      e[4] = (_Float16)f2.x; e[5] = (_Float16)f2.z;
      e[6] = (_Float16)f3.x; e[7] = (_Float16)f3.z;
      o[0] = (_Float16)f0.y; o[1] = (_Float16)f0.w;
      o[2] = (_Float16)f1.y; o[3] = (_Float16)f1.w;
      o[4] = (_Float16)f2.y; o[5] = (_Float16)f2.w;
      o[6] = (_Float16)f3.y; o[7] = (_Float16)f3.w;
      wfrag[g][kt2] = e;
      wfrag[g][kt2 + 4] = o;
    }
  }

  // drain bias-slot store (read at t=0 by r>0 lanes) + h_lds zero barrier
  asm volatile("s_waitcnt vmcnt(0)" ::: "memory");
  __syncthreads();

  float c[4] = {0.f, 0.f, 0.f, 0.f};
  float4 outb[4];
#pragma unroll
  for (int i = 0; i < 4; i++) outb[i] = make_float4(0.f, 0.f, 0.f, 0.f);

  const int ebl = L >> 5;
  const int eu = (L & 31) * 4;
  const int exp_idx = bl * 32 + 4 * wv + quad;

  const bool is_cons = (wv == 0) && (rgr > 0);

  // ---- incremental pointers ----
  const __half* zpp = zph + ((size_t)b * HH + r) * WW * 512 + zoff;
  const __half* zbias = zph + (size_t)BB * HH * WW * 512 + blk * 512 + zoff;
  const unsigned long long* ca =
      hx + (((size_t)(rgr > 0 ? rgr - 1 : 0) * 4 + bg) * 64 + L);
  unsigned long long* pa_hx = hx + (((size_t)rgr * 4 + bg) * 64 + exp_idx);
  float* op0 = out + (((size_t)b * HID + uq0 + 0) * HH + r) * WW;
  float* op1 = out + (((size_t)b * HID + uq0 + 1) * HH + r) * WW;
  float* op2 = out + (((size_t)b * HID + uq0 + 2) * HH + r) * WW;
  float* op3 = out + (((size_t)b * HID + uq0 + 3) * HH + r) * WW;

  // ---- zph readiness flag for this lane's (b,r) tile ----
  unsigned* zf = &zflag[r * 8 + b];
  bool zdone = false;

  // ---- zp for t=0 (w0 = -r: in-band only for r==0) ----
  union ZU {
    uint4 q[2];
    __half h[16];
  } zu;
  {
    if (r == 0) {  // r==0 lanes read real zph at t=0: wait for their tile
      while (__hip_atomic_load(zf, __ATOMIC_RELAXED,
                               __HIP_MEMORY_SCOPE_AGENT) == 0u)
        __builtin_amdgcn_s_sleep(2);
      __builtin_amdgcn_fence(__ATOMIC_ACQUIRE, "agent");
      zdone = true;
    }
    const uint4* p0 = (const uint4*)((r == 0) ? zpp : zbias);
    zu.q[0] = p0[0];
    zu.q[1] = p0[1];
  }
  int wn = 1 - r;
  const __half* zcur = zpp + (ptrdiff_t)wn * 512;

  __syncthreads();

  // 126 = 63x2 steps with static read-buffer index, then epilogue t=126.
  for (int t = 0; t < TT - 1; t += 2) {
    STEP_BODY(t, 0);
    STEP_BODY(t + 1, 1);
  }
  STEP_BODY(TT - 1, 0);
}

// ================= round-1 fallback path (proven correct) =================
__global__ __launch_bounds__(256) void transpose_x(const float* __restrict__ x,
                                                   float* __restrict__ xT) {
  int b = blockIdx.x >> 6;
  int r = blockIdx.x & 63;
  __shared__ float tile[32][65];
  for (int cc = 0; cc < 4; cc++) {
    int cl = threadIdx.x >> 6;
    int w = threadIdx.x & 63;
#pragma unroll
    for (int k = 0; k < 8; k++) {
      int c_loc = k * 4 + cl;
      int c = cc * 32 + c_loc;
      tile[c_loc][w] = x[(((size_t)b * 128 + c) * HH + r) * WW + w];
    }
    __syncthreads();
    int cs = threadIdx.x & 31;
    int wp = threadIdx.x >> 5;
#pragma unroll
    for (int k = 0; k < 8; k++) {
      int w2 = wp * 8 + k;
      xT[(((size_t)b * HH + r) * WW + w2) * 128 + cc * 32 + cs] = tile[cs][w2];
    }
    __syncthreads();
  }
}

__global__ __launch_bounds__(256) void step_kernel(
    const float* __restrict__ x, const float* __restrict__ xT, int use_xT,
    const float* __restrict__ w_is, const float* __restrict__ b_is,
    const float* __restrict__ w_ss, const float* __restrict__ b_ss,
    const float* __restrict__ h_prev, float* __restrict__ h_next,
    float* __restrict__ c_state, float* __restrict__ out, int t) {
  const int rg = blockIdx.x;
  const int q = blockIdx.y;
  const int r0 = rg * 2;
  const int tid = threadIdx.x;
  const int o_loc = tid & 63;
  const int k4 = tid >> 6;
  const int g_ = o_loc >> 4;
  const int u_ = o_loc & 15;
  const int O = g_ * 128 + q * 16 + u_;
  const int i0 = k4 * 32;

  __shared__ __align__(16) float h_in[3][BB][HID];
  __shared__ float zred[16][4][65];

  for (int idx = tid; idx < 3 * BB * HID; idx += 256) {
    int row_sel = idx >> 10;
    int rem = idx & 1023;
    int b = rem >> 7;
    int u = rem & 127;
    int rr = r0 - 1 + row_sel;
    h_in[row_sel][b][u] = (rr >= 0) ? h_prev[((size_t)b * HH + rr) * HID + u] : 0.0f;
  }

  float wr0[32], wr1[32], wz[32];
  {
    const float4* wss4 = (const float4*)(w_ss + ((size_t)O * 128 + i0) * 2);
#pragma unroll
    for (int j = 0; j < 16; j++) {
      float4 v = wss4[j];
      wr0[2 * j] = v.x;
      wr1[2 * j] = v.y;
      wr0[2 * j + 1] = v.z;
      wr1[2 * j + 1] = v.w;
    }
    const float4* wis4 = (const float4*)(w_is + (size_t)O * 128 + i0);
#pragma unroll
    for (int j = 0; j < 8; j++) {
      float4 v = wis4[j];
      wz[4 * j] = v.x;
      wz[4 * j + 1] = v.y;
      wz[4 * j + 2] = v.z;
      wz[4 * j + 3] = v.w;
    }
  }

  __syncthreads();

  float acc[2][BB];
#pragma unroll
  for (int rl = 0; rl < 2; rl++)
#pragma unroll
    for (int b = 0; b < BB; b++) acc[rl][b] = 0.0f;

#pragma unroll
  for (int jb = 0; jb < 8; jb++) {
    int ib = i0 + jb * 4;
#pragma unroll
    for (int b = 0; b < BB; b++) {
      const float4 hm4 = *(const float4*)&h_in[0][b][ib];
      const float4 hc4 = *(const float4*)&h_in[1][b][ib];
      const float4 hp4 = *(const float4*)&h_in[2][b][ib];
      const float* hm = (const float*)&hm4;
      const float* hc = (const float*)&hc4;
      const float* hq = (const float*)&hp4;
#pragma unroll
      for (int jj = 0; jj < 4; jj++) {
        float w0v = wr0[jb * 4 + jj];
        float w1v = wr1[jb * 4 + jj];
        acc[0][b] += w0v * hm[jj] + w1v * hc[jj];
        acc[1][b] += w0v * hc[jj] + w1v * hq[jj];
      }
    }
  }

#pragma unroll
  for (int rl = 0; rl < 2; rl++) {
    int rr = r0 + rl;
    int wcol = t - rr;
    if (wcol >= 0 && wcol < WW) {
      if (use_xT) {
        for (int b = 0; b < BB; b++) {
          const float4* xp =
              (const float4*)(xT + (((size_t)b * HH + rr) * WW + wcol) * 128 + i0);
#pragma unroll
          for (int j = 0; j < 8; j++) {
            float4 v = xp[j];
            acc[rl][b] += wz[4 * j] * v.x + wz[4 * j + 1] * v.y +
                          wz[4 * j + 2] * v.z + wz[4 * j + 3] * v.w;
          }
        }
      } else {
        for (int b = 0; b < BB; b++) {
          const float* xb = x + (((size_t)b * 128 + i0) * HH + rr) * WW + wcol;
#pragma unroll
          for (int j = 0; j < 32; j++) {
            acc[rl][b] += wz[j] * xb[(size_t)j * HH * WW];
          }
        }
      }
    }
  }

#pragma unroll
  for (int rl = 0; rl < 2; rl++)
#pragma unroll
    for (int b = 0; b < BB; b++) zred[rl * 8 + b][k4][o_loc] = acc[rl][b];
  __syncthreads();

  {
    int u = tid >> 4;
    int cell = tid & 15;
    int rl = cell >> 3;
    int b = cell & 7;
    int rr = r0 + rl;
    float z[4];
#pragma unroll
    for (int gg = 0; gg < 4; gg++) {
      int ol = gg * 16 + u;
      float s = zred[cell][0][ol] + zred[cell][1][ol] + zred[cell][2][ol] +
                zred[cell][3][ol];
      int Og = gg * 128 + q * 16 + u;
      z[gg] = s + b_is[Og] + b_ss[Og];
    }
    float iv = 1.0f / (1.0f + expf(-z[0]));
    float fv = 1.0f / (1.0f + expf(-z[1]));
    float ov = 1.0f / (1.0f + expf(-z[2]));
    float gv = tanhf(z[3]);
    int U = q * 16 + u;
    size_t sidx = ((size_t)b * HH + rr) * HID + U;
    float cv = c_state[sidx];
    float cn = fv * cv + iv * gv;
    c_state[sidx] = cn;
    float hn = ov * tanhf(cn);
    h_next[sidx] = hn;
    int wcol = t - rr;
    if (wcol >= 0 && wcol < WW) {
      out[(((size_t)b * HID + U) * HH + rr) * WW + wcol] = hn;
    }
  }
}

extern "C" void kernel_launch(void* const* d_in, const int* in_sizes, int n_in,
                              void* d_out, int out_size, void* d_ws,
                              size_t ws_size, hipStream_t stream) {
  const float* x = (const float*)d_in[0];
  const float* w_is = (const float*)d_in[1];
  const float* b_is = (const float*)d_in[2];
  const float* w_ss = (const float*)d_in[3];
  const float* b_ss = (const float*)d_in[4];
  float* outp = (float*)d_out;

  // zph: tiles + 32 per-lstm-block private bias slots (512 halfs each)
  const size_t zph_bytes = ((size_t)BB * HH * WW * 512 + 32 * 512) * 2;
  const size_t hx_bytes = (size_t)TT * 8 * 4 * 64 * 8;
  const size_t zflag_bytes = 512 * sizeof(unsigned);
  const size_t need = zph_bytes + hx_bytes + zflag_bytes;

  char* ws = (char*)d_ws;
  if (ws_size >= need) {
    __half* zph = (__half*)ws;
    unsigned long long* hx = (unsigned long long*)(ws + zph_bytes);
    unsigned* zflag = (unsigned*)(ws + zph_bytes + hx_bytes);

    // hx sentinel = 0xFF byte fill (== SENT64); zflag = 0. Memsets are
    // graph-capture-safe (used by the proven fallback path).
    hipMemsetAsync(hx, 0xFF, hx_bytes, stream);
    hipMemsetAsync(zflag, 0, zflag_bytes, stream);
    // single fused launch: 32 lstm + 128 zpre = 160 blocks (1 block/CU)
    fused<<<dim3(32 + NZB), 512, 0, stream>>>(zph, hx, outp, x, w_is, w_ss,
                                              b_is, b_ss, zflag, zph);
  } else {
    // -------- round-1 fallback --------
    const size_t xT_elems = (size_t)BB * HH * WW * 128;
    const size_t st_elems = (size_t)BB * HH * HID;
    const size_t need_xT = (xT_elems + 3 * st_elems) * sizeof(float);
    float* wsf = (float*)d_ws;
    float* xT = nullptr;
    float* st;
    int use_xT = 0;
    if (ws_size >= need_xT) {
      use_xT = 1;
      xT = wsf;
      st = wsf + xT_elems;
    } else {
      st = wsf;
    }
    float* h0 = st;
    float* h1 = st + st_elems;
    float* cb = st + 2 * st_elems;
    hipMemsetAsync(st, 0, 3 * st_elems * sizeof(float), stream);
    if (use_xT) transpose_x<<<dim3(BB * HH), 256, 0, stream>>>(x, xT);
    for (int t = 0; t < TT; t++) {
      float* hp = (t & 1) ? h1 : h0;
      float* hn = (t & 1) ? h0 : h1;
      step_kernel<<<dim3(32, 8), 256, 0, stream>>>(x, xT, use_xT, w_is, b_is,
                                                   w_ss, b_ss, hp, hn, cb, outp,
                                                   t);
    }
  }
}